// Round 11
// baseline (134.589 us; speedup 1.0000x reference)
//
#include <hip/hip_runtime.h>
#include <hip/hip_bf16.h>
#include <math.h>

// x: (B=16, S=512, T=64, F=256) fp32.  rows = B*S = 8192, tile = T*F = 16384 floats.
// out[row][f] = sum_t softmax_t( sum_f' x[row][t][f'] * wq[row][f'] ) * x[row][t][f]
// wq[row][f]  = sum_d W[f][d] * x[row][63][d]

#define TT 64
#define FF 256
#define KC 64   // K-chunk in wq GEMM
#define PAD 68  // LDS row pitch (floats): 16B-aligned b128, 68%32=4 -> 2-way max

typedef float v4f __attribute__((ext_vector_type(4)));

__device__ __forceinline__ float4 ntload4(const float* p) {
    v4f t = __builtin_nontemporal_load(reinterpret_cast<const v4f*>(p));
    float4 r; r.x = t.x; r.y = t.y; r.z = t.z; r.w = t.w;
    return r;
}

// ---------------- kernel 1: wq = q @ W^T register-tiled GEMM (R9 measured-best, 64x64 tile) ----------------
__global__ __launch_bounds__(256) void wq_gemm(const float* __restrict__ x,
                                               const float* __restrict__ W,
                                               float* __restrict__ wq) {
    __shared__ float qs[KC][PAD];
    __shared__ float ws[KC][PAD];

    const int tid = threadIdx.x;
    const int r0 = (blockIdx.x >> 2) * 64;
    const int f0 = (blockIdx.x & 3) * 64;

    const int tf = tid & 15;
    const int tr = tid >> 4;

    const int sc = tid & 15;
    const int sr = tid >> 4;

    float4 acc[4];
#pragma unroll
    for (int j = 0; j < 4; ++j) acc[j] = make_float4(0.f, 0.f, 0.f, 0.f);

    for (int k0 = 0; k0 < FF; k0 += KC) {
        __syncthreads();
#pragma unroll
        for (int p = 0; p < 4; ++p) {
            int r = sr + 16 * p;
            float4 v = *reinterpret_cast<const float4*>(
                x + (size_t)(r0 + r) * (TT * FF) + (size_t)(TT - 1) * FF + k0 + 4 * sc);
            qs[4 * sc + 0][r] = v.x;
            qs[4 * sc + 1][r] = v.y;
            qs[4 * sc + 2][r] = v.z;
            qs[4 * sc + 3][r] = v.w;
            float4 u = *reinterpret_cast<const float4*>(
                W + (size_t)(f0 + r) * FF + k0 + 4 * sc);
            ws[4 * sc + 0][r] = u.x;
            ws[4 * sc + 1][r] = u.y;
            ws[4 * sc + 2][r] = u.z;
            ws[4 * sc + 3][r] = u.w;
        }
        __syncthreads();

#pragma unroll
        for (int k = 0; k < KC; ++k) {
            float4 qv = *reinterpret_cast<const float4*>(&qs[k][4 * tr]);
            float4 wv = *reinterpret_cast<const float4*>(&ws[k][4 * tf]);
            acc[0].x = fmaf(qv.x, wv.x, acc[0].x);
            acc[0].y = fmaf(qv.x, wv.y, acc[0].y);
            acc[0].z = fmaf(qv.x, wv.z, acc[0].z);
            acc[0].w = fmaf(qv.x, wv.w, acc[0].w);
            acc[1].x = fmaf(qv.y, wv.x, acc[1].x);
            acc[1].y = fmaf(qv.y, wv.y, acc[1].y);
            acc[1].z = fmaf(qv.y, wv.z, acc[1].z);
            acc[1].w = fmaf(qv.y, wv.w, acc[1].w);
            acc[2].x = fmaf(qv.z, wv.x, acc[2].x);
            acc[2].y = fmaf(qv.z, wv.y, acc[2].y);
            acc[2].z = fmaf(qv.z, wv.z, acc[2].z);
            acc[2].w = fmaf(qv.z, wv.w, acc[2].w);
            acc[3].x = fmaf(qv.w, wv.x, acc[3].x);
            acc[3].y = fmaf(qv.w, wv.y, acc[3].y);
            acc[3].z = fmaf(qv.w, wv.z, acc[3].z);
            acc[3].w = fmaf(qv.w, wv.w, acc[3].w);
        }
    }

#pragma unroll
    for (int j = 0; j < 4; ++j)
        *reinterpret_cast<float4*>(
            wq + (size_t)(r0 + 4 * tr + j) * FF + f0 + 4 * tf) = acc[j];
}

// fold-reduce for 4 rows + wave-max (R9 logic, factored)
__device__ __forceinline__ void fold4(const float p[4], int lane, float& y, float& mw) {
    const bool b5 = (lane & 32) != 0;
    const bool b4 = (lane & 16) != 0;
    float s2a, s2b;
    { float send = b5 ? p[0] : p[2]; float recv = __shfl_xor(send, 32, 64); s2a = (b5 ? p[2] : p[0]) + recv; }
    { float send = b5 ? p[1] : p[3]; float recv = __shfl_xor(send, 32, 64); s2b = (b5 ? p[3] : p[1]) + recv; }
    { float send = b4 ? s2a : s2b; float recv = __shfl_xor(send, 16, 64); y = (b4 ? s2b : s2a) + recv; }
    y += __shfl_xor(y, 8, 64);
    y += __shfl_xor(y, 4, 64);
    y += __shfl_xor(y, 2, 64);
    y += __shfl_xor(y, 1, 64);                      // full score of row lane>>4
    mw = y;
    mw = fmaxf(mw, __shfl_xor(mw, 16, 64));
    mw = fmaxf(mw, __shfl_xor(mw, 32, 64));
}

// ---------------- kernel 2: attention, 4 rows/block, register double-buffered prefetch ----------------
// 1024 threads = 16 waves x 4 t-rows per row-pass. Row r+1's x loads issue before
// row r's compute -> HBM fetch overlaps fold/softmax tail. LDS ping-pong (r&1).
__global__ __launch_bounds__(1024, 8) void attn_pipe(const float* __restrict__ x,
                                                     const float* __restrict__ wq,
                                                     float* __restrict__ out) {
    const int tid  = threadIdx.x;
    const int lane = tid & 63;
    const int w    = tid >> 6;        // wave 0..15, owns t = 4w .. 4w+3
    const size_t r0 = (size_t)blockIdx.x * 4;

    __shared__ float sc[2][TT];
    __shared__ float mb[2][16];
    __shared__ float lb[2][16];
    __shared__ float part[2][16][FF];

    float4 xvA[4], xvB[4];
    float4 wqA, wqB;

    const float* xt0 = x + r0 * (TT * FF) + (size_t)(w * 4) * FF + 4 * lane;

#pragma unroll
    for (int j = 0; j < 4; ++j) xvA[j] = ntload4(xt0 + (size_t)j * FF);
    wqA = *reinterpret_cast<const float4*>(wq + r0 * FF + 4 * lane);

#define ROW(r, XV, WQ, NXV, NWQ, PF) do {                                        \
    if (PF) {                                                                    \
        const float* xtn = xt0 + (size_t)((r) + 1) * (TT * FF);                  \
        _Pragma("unroll")                                                        \
        for (int j = 0; j < 4; ++j) NXV[j] = ntload4(xtn + (size_t)j * FF);      \
        NWQ = *reinterpret_cast<const float4*>(wq + (r0 + (r) + 1) * FF + 4 * lane); \
    }                                                                            \
    float p[4];                                                                  \
    _Pragma("unroll")                                                            \
    for (int j = 0; j < 4; ++j)                                                  \
        p[j] = XV[j].x * WQ.x + XV[j].y * WQ.y + XV[j].z * WQ.z + XV[j].w * WQ.w;\
    float y, mw;                                                                 \
    fold4(p, lane, y, mw);                                                       \
    if ((lane & 15) == 0) sc[(r) & 1][w * 4 + (lane >> 4)] = y;                  \
    if (lane == 0) mb[(r) & 1][w] = mw;                                          \
    __syncthreads();                                                             \
    float m = mb[(r) & 1][0];                                                    \
    _Pragma("unroll")                                                            \
    for (int i = 1; i < 16; ++i) m = fmaxf(m, mb[(r) & 1][i]);                   \
    float wt[4]; float lw = 0.f;                                                 \
    _Pragma("unroll")                                                            \
    for (int j = 0; j < 4; ++j) { wt[j] = __expf(sc[(r) & 1][w * 4 + j] - m); lw += wt[j]; } \
    float4 acc = make_float4(0.f, 0.f, 0.f, 0.f);                                \
    _Pragma("unroll")                                                            \
    for (int j = 0; j < 4; ++j) {                                                \
        acc.x += wt[j] * XV[j].x; acc.y += wt[j] * XV[j].y;                      \
        acc.z += wt[j] * XV[j].z; acc.w += wt[j] * XV[j].w;                      \
    }                                                                            \
    *reinterpret_cast<float4*>(&part[(r) & 1][w][4 * lane]) = acc;               \
    if (lane == 0) lb[(r) & 1][w] = lw;                                          \
    __syncthreads();                                                             \
    if (tid < FF) {                                                              \
        float l = 0.f;                                                           \
        _Pragma("unroll")                                                        \
        for (int i = 0; i < 16; ++i) l += lb[(r) & 1][i];                        \
        float v = 0.f;                                                           \
        _Pragma("unroll")                                                        \
        for (int i = 0; i < 16; ++i) v += part[(r) & 1][i][tid];                 \
        __builtin_nontemporal_store(v / l, out + (r0 + (r)) * FF + tid);         \
    }                                                                            \
} while (0)

    ROW(0, xvA, wqA, xvB, wqB, true);
    ROW(1, xvB, wqB, xvA, wqA, true);
    ROW(2, xvA, wqA, xvB, wqB, true);
    ROW(3, xvB, wqB, xvA, wqA, false);
#undef ROW
}

// ---------------- fallback: fully fused (only if ws too small) ----------------
__device__ __forceinline__ void attn_row_fb(const float* __restrict__ xt,
                                            float4 wqv,
                                            float* __restrict__ out_row,
                                            int tid) {
    const int lane = tid & 63;
    const int w    = tid >> 6;

    __shared__ float scf[TT];
    __shared__ float partf[4][FF];

    float4 xv[16];
#pragma unroll
    for (int j = 0; j < 16; ++j)
        xv[j] = *reinterpret_cast<const float4*>(xt + (size_t)(w * 16 + j) * FF + 4 * lane);

#pragma unroll
    for (int j = 0; j < 16; ++j) {
        float s = xv[j].x * wqv.x + xv[j].y * wqv.y + xv[j].z * wqv.z + xv[j].w * wqv.w;
#pragma unroll
        for (int off = 32; off > 0; off >>= 1)
            s += __shfl_xor(s, off, 64);
        if (lane == 0) scf[w * 16 + j] = s;
    }
    __syncthreads();

    float m = -INFINITY;
#pragma unroll
    for (int t = 0; t < TT; ++t) m = fmaxf(m, scf[t]);
    float l = 0.f;
#pragma unroll
    for (int t = 0; t < TT; ++t) l += __expf(scf[t] - m);

    float4 acc = make_float4(0.f, 0.f, 0.f, 0.f);
#pragma unroll
    for (int j = 0; j < 16; ++j) {
        float wt = __expf(scf[w * 16 + j] - m);
        acc.x += wt * xv[j].x;
        acc.y += wt * xv[j].y;
        acc.z += wt * xv[j].z;
        acc.w += wt * xv[j].w;
    }
    *reinterpret_cast<float4*>(&partf[w][4 * lane]) = acc;
    __syncthreads();

    float v = partf[0][tid] + partf[1][tid] + partf[2][tid] + partf[3][tid];
    out_row[tid] = v / l;
}

__global__ __launch_bounds__(256) void fused_kernel(const float* __restrict__ x,
                                                    const float* __restrict__ W,
                                                    float* __restrict__ out) {
    const int row = blockIdx.x;
    const int tid = threadIdx.x;
    const int lane = tid & 63;
    const float* xt = x + (size_t)row * (TT * FF);

    __shared__ float q[FF];
    __shared__ float wqs[FF];
    if (tid < 64) {
        float4 v = *reinterpret_cast<const float4*>(xt + (size_t)(TT - 1) * FF + tid * 4);
        *reinterpret_cast<float4*>(&q[tid * 4]) = v;
    }
    __syncthreads();

    float a = 0.f;
    const float* wrow = W + (size_t)tid * FF;
    for (int d0 = 0; d0 < FF; d0 += 4) {
        float4 wv = *reinterpret_cast<const float4*>(wrow + d0);
        float4 qv = *reinterpret_cast<const float4*>(&q[d0]);
        a += wv.x * qv.x + wv.y * qv.y + wv.z * qv.z + wv.w * qv.w;
    }
    wqs[tid] = a;
    __syncthreads();

    float4 wqv = *reinterpret_cast<const float4*>(&wqs[4 * lane]);
    attn_row_fb(xt, wqv, out + (size_t)row * FF, tid);
}

extern "C" void kernel_launch(void* const* d_in, const int* in_sizes, int n_in,
                              void* d_out, int out_size, void* d_ws, size_t ws_size,
                              hipStream_t stream) {
    (void)n_in; (void)out_size;
    const float* x = (const float*)d_in[0];
    const float* W = (const float*)d_in[1];
    float* out = (float*)d_out;

    const int rows = in_sizes[0] / (TT * FF);   // 8192
    const size_t wq_bytes = (size_t)rows * FF * sizeof(float);

    if (ws_size >= wq_bytes) {
        float* wq = (float*)d_ws;
        wq_gemm<<<(rows / 64) * 4, 256, 0, stream>>>(x, W, wq);
        attn_pipe<<<rows / 4, 1024, 0, stream>>>(x, wq, out);
    } else {
        fused_kernel<<<rows, 256, 0, stream>>>(x, W, out);
    }
}

// Round 12
// 113.158 us; speedup vs baseline: 1.1894x; 1.1894x over previous
//
#include <hip/hip_runtime.h>
#include <hip/hip_bf16.h>
#include <math.h>

// x: (B=16, S=512, T=64, F=256) fp32.  rows = B*S = 8192, tile = T*F = 16384 floats.
// out[row][f] = sum_t softmax_t( sum_f' x[row][t][f'] * wq[row][f'] ) * x[row][t][f]
// wq[row][f]  = sum_d W[f][d] * x[row][63][d]
//
// Measured-best configuration (R9, 113.4 µs):
//   wq_gemm: 64x64 register-tiled GEMM, 512 blocks        (~14 µs, LDS-throughput floor)
//   attn_kernel4: 1024 thr = 16 waves x 4 t-rows, NT loads (~99.5 µs = 5.28 TB/s read)
// Refuted alternatives: wave-per-row online softmax (R3), 8-wave (R5 tie),
// scalarized/coalesced wq (R3/R5), 32x64 wq tile (R10), explicit prefetch pipeline (R11).

#define TT 64
#define FF 256
#define KC 64   // K-chunk in wq GEMM
#define PAD 68  // LDS row pitch (floats): 16B-aligned b128, 68%32=4 -> 2-way max

typedef float v4f __attribute__((ext_vector_type(4)));

__device__ __forceinline__ float4 ntload4(const float* p) {
    v4f t = __builtin_nontemporal_load(reinterpret_cast<const v4f*>(p));
    float4 r; r.x = t.x; r.y = t.y; r.z = t.z; r.w = t.w;
    return r;
}

// ---------------- kernel 1: wq = q @ W^T register-tiled GEMM (64x64 tile) ----------------
__global__ __launch_bounds__(256) void wq_gemm(const float* __restrict__ x,
                                               const float* __restrict__ W,
                                               float* __restrict__ wq) {
    __shared__ float qs[KC][PAD];
    __shared__ float ws[KC][PAD];

    const int tid = threadIdx.x;
    const int r0 = (blockIdx.x >> 2) * 64;
    const int f0 = (blockIdx.x & 3) * 64;

    const int tf = tid & 15;
    const int tr = tid >> 4;

    const int sc = tid & 15;
    const int sr = tid >> 4;

    float4 acc[4];
#pragma unroll
    for (int j = 0; j < 4; ++j) acc[j] = make_float4(0.f, 0.f, 0.f, 0.f);

    for (int k0 = 0; k0 < FF; k0 += KC) {
        __syncthreads();
#pragma unroll
        for (int p = 0; p < 4; ++p) {
            int r = sr + 16 * p;
            float4 v = *reinterpret_cast<const float4*>(
                x + (size_t)(r0 + r) * (TT * FF) + (size_t)(TT - 1) * FF + k0 + 4 * sc);
            qs[4 * sc + 0][r] = v.x;
            qs[4 * sc + 1][r] = v.y;
            qs[4 * sc + 2][r] = v.z;
            qs[4 * sc + 3][r] = v.w;
            float4 u = *reinterpret_cast<const float4*>(
                W + (size_t)(f0 + r) * FF + k0 + 4 * sc);
            ws[4 * sc + 0][r] = u.x;
            ws[4 * sc + 1][r] = u.y;
            ws[4 * sc + 2][r] = u.z;
            ws[4 * sc + 3][r] = u.w;
        }
        __syncthreads();

#pragma unroll
        for (int k = 0; k < KC; ++k) {
            float4 qv = *reinterpret_cast<const float4*>(&qs[k][4 * tr]);
            float4 wv = *reinterpret_cast<const float4*>(&ws[k][4 * tf]);
            acc[0].x = fmaf(qv.x, wv.x, acc[0].x);
            acc[0].y = fmaf(qv.x, wv.y, acc[0].y);
            acc[0].z = fmaf(qv.x, wv.z, acc[0].z);
            acc[0].w = fmaf(qv.x, wv.w, acc[0].w);
            acc[1].x = fmaf(qv.y, wv.x, acc[1].x);
            acc[1].y = fmaf(qv.y, wv.y, acc[1].y);
            acc[1].z = fmaf(qv.y, wv.z, acc[1].z);
            acc[1].w = fmaf(qv.y, wv.w, acc[1].w);
            acc[2].x = fmaf(qv.z, wv.x, acc[2].x);
            acc[2].y = fmaf(qv.z, wv.y, acc[2].y);
            acc[2].z = fmaf(qv.z, wv.z, acc[2].z);
            acc[2].w = fmaf(qv.z, wv.w, acc[2].w);
            acc[3].x = fmaf(qv.w, wv.x, acc[3].x);
            acc[3].y = fmaf(qv.w, wv.y, acc[3].y);
            acc[3].z = fmaf(qv.w, wv.z, acc[3].z);
            acc[3].w = fmaf(qv.w, wv.w, acc[3].w);
        }
    }

#pragma unroll
    for (int j = 0; j < 4; ++j)
        *reinterpret_cast<float4*>(
            wq + (size_t)(r0 + 4 * tr + j) * FF + f0 + 4 * tf) = acc[j];
}

// ---------------- kernel 2: attention, 1024 threads = 16 waves x 4 t-rows ----------------
__global__ __launch_bounds__(1024, 8) void attn_kernel4(const float* __restrict__ x,
                                                        const float* __restrict__ wq,
                                                        float* __restrict__ out) {
    const int tid  = threadIdx.x;
    const int lane = tid & 63;
    const int w    = tid >> 6;        // wave 0..15, owns t = 4w .. 4w+3
    const int row  = blockIdx.x;
    const float* xt = x + (size_t)row * (TT * FF);

    __shared__ float sc[TT];
    __shared__ float mbuf[16];
    __shared__ float lbuf[16];
    __shared__ float part[16][FF];

    float4 wqv = *reinterpret_cast<const float4*>(wq + (size_t)row * FF + 4 * lane);

    // 4 rows in registers, NT (x never re-read: evict-first)
    float4 xv[4];
#pragma unroll
    for (int j = 0; j < 4; ++j)
        xv[j] = ntload4(xt + (size_t)(w * 4 + j) * FF + 4 * lane);

    float p[4];
#pragma unroll
    for (int j = 0; j < 4; ++j)
        p[j] = xv[j].x * wqv.x + xv[j].y * wqv.y + xv[j].z * wqv.z + xv[j].w * wqv.w;

    // fold-reduce: 4 row-sums across 64 lanes in 6 shuffles
    const bool b5 = (lane & 32) != 0;
    const bool b4 = (lane & 16) != 0;

    float s2[2];
#pragma unroll
    for (int j = 0; j < 2; ++j) {
        float send = b5 ? p[j] : p[j + 2];
        float recv = __shfl_xor(send, 32, 64);
        s2[j] = (b5 ? p[j + 2] : p[j]) + recv;      // row = 2*b5 + j
    }
    float y;
    {
        float send = b4 ? s2[0] : s2[1];
        float recv = __shfl_xor(send, 16, 64);
        y = (b4 ? s2[1] : s2[0]) + recv;            // row = lane>>4
    }
    y += __shfl_xor(y, 8, 64);
    y += __shfl_xor(y, 4, 64);
    y += __shfl_xor(y, 2, 64);
    y += __shfl_xor(y, 1, 64);                      // full score of row lane>>4

    float mw = y;
    mw = fmaxf(mw, __shfl_xor(mw, 16, 64));
    mw = fmaxf(mw, __shfl_xor(mw, 32, 64));

    if ((lane & 15) == 0) sc[w * 4 + (lane >> 4)] = y;
    if (lane == 0) mbuf[w] = mw;
    __syncthreads();

    float m = mbuf[0];
#pragma unroll
    for (int i = 1; i < 16; ++i) m = fmaxf(m, mbuf[i]);

    float wt[4];
    float lw = 0.f;
#pragma unroll
    for (int j = 0; j < 4; ++j) {
        wt[j] = __expf(sc[w * 4 + j] - m);
        lw += wt[j];
    }

    float4 acc = make_float4(0.f, 0.f, 0.f, 0.f);
#pragma unroll
    for (int j = 0; j < 4; ++j) {
        acc.x += wt[j] * xv[j].x;
        acc.y += wt[j] * xv[j].y;
        acc.z += wt[j] * xv[j].z;
        acc.w += wt[j] * xv[j].w;
    }
    *reinterpret_cast<float4*>(&part[w][4 * lane]) = acc;
    if (lane == 0) lbuf[w] = lw;
    __syncthreads();

    if (tid < FF) {
        float l = 0.f;
#pragma unroll
        for (int i = 0; i < 16; ++i) l += lbuf[i];
        float v = 0.f;
#pragma unroll
        for (int i = 0; i < 16; ++i) v += part[i][tid];
        __builtin_nontemporal_store(v / l, out + (size_t)row * FF + tid);
    }
}

// ---------------- fallback: fully fused (only if ws too small) ----------------
__device__ __forceinline__ void attn_row_fb(const float* __restrict__ xt,
                                            float4 wqv,
                                            float* __restrict__ out_row,
                                            int tid) {
    const int lane = tid & 63;
    const int w    = tid >> 6;

    __shared__ float scf[TT];
    __shared__ float partf[4][FF];

    float4 xv[16];
#pragma unroll
    for (int j = 0; j < 16; ++j)
        xv[j] = *reinterpret_cast<const float4*>(xt + (size_t)(w * 16 + j) * FF + 4 * lane);

#pragma unroll
    for (int j = 0; j < 16; ++j) {
        float s = xv[j].x * wqv.x + xv[j].y * wqv.y + xv[j].z * wqv.z + xv[j].w * wqv.w;
#pragma unroll
        for (int off = 32; off > 0; off >>= 1)
            s += __shfl_xor(s, off, 64);
        if (lane == 0) scf[w * 16 + j] = s;
    }
    __syncthreads();

    float m = -INFINITY;
#pragma unroll
    for (int t = 0; t < TT; ++t) m = fmaxf(m, scf[t]);
    float l = 0.f;
#pragma unroll
    for (int t = 0; t < TT; ++t) l += __expf(scf[t] - m);

    float4 acc = make_float4(0.f, 0.f, 0.f, 0.f);
#pragma unroll
    for (int j = 0; j < 16; ++j) {
        float wt = __expf(scf[w * 16 + j] - m);
        acc.x += wt * xv[j].x;
        acc.y += wt * xv[j].y;
        acc.z += wt * xv[j].z;
        acc.w += wt * xv[j].w;
    }
    *reinterpret_cast<float4*>(&partf[w][4 * lane]) = acc;
    __syncthreads();

    float v = partf[0][tid] + partf[1][tid] + partf[2][tid] + partf[3][tid];
    out_row[tid] = v / l;
}

__global__ __launch_bounds__(256) void fused_kernel(const float* __restrict__ x,
                                                    const float* __restrict__ W,
                                                    float* __restrict__ out) {
    const int row = blockIdx.x;
    const int tid = threadIdx.x;
    const int lane = tid & 63;
    const float* xt = x + (size_t)row * (TT * FF);

    __shared__ float q[FF];
    __shared__ float wqs[FF];
    if (tid < 64) {
        float4 v = *reinterpret_cast<const float4*>(xt + (size_t)(TT - 1) * FF + tid * 4);
        *reinterpret_cast<float4*>(&q[tid * 4]) = v;
    }
    __syncthreads();

    float a = 0.f;
    const float* wrow = W + (size_t)tid * FF;
    for (int d0 = 0; d0 < FF; d0 += 4) {
        float4 wv = *reinterpret_cast<const float4*>(wrow + d0);
        float4 qv = *reinterpret_cast<const float4*>(&q[d0]);
        a += wv.x * qv.x + wv.y * qv.y + wv.z * qv.z + wv.w * qv.w;
    }
    wqs[tid] = a;
    __syncthreads();

    float4 wqv = *reinterpret_cast<const float4*>(&wqs[4 * lane]);
    attn_row_fb(xt, wqv, out + (size_t)row * FF, tid);
}

extern "C" void kernel_launch(void* const* d_in, const int* in_sizes, int n_in,
                              void* d_out, int out_size, void* d_ws, size_t ws_size,
                              hipStream_t stream) {
    (void)n_in; (void)out_size;
    const float* x = (const float*)d_in[0];
    const float* W = (const float*)d_in[1];
    float* out = (float*)d_out;

    const int rows = in_sizes[0] / (TT * FF);   // 8192
    const size_t wq_bytes = (size_t)rows * FF * sizeof(float);

    if (ws_size >= wq_bytes) {
        float* wq = (float*)d_ws;
        wq_gemm<<<(rows / 64) * 4, 256, 0, stream>>>(x, W, wq);
        attn_kernel4<<<rows, 1024, 0, stream>>>(x, wq, out);
    } else {
        fused_kernel<<<rows, 256, 0, stream>>>(x, W, out);
    }
}